// Round 3
// baseline (1295.564 us; speedup 1.0000x reference)
//
#include <hip/hip_runtime.h>

// ---------------------------------------------------------------------------
// FrozenSoftmaxAttention: B=4, L=4096, d=dv=dh=512
//   Qh = K@Wq^T, Kh = K@Wk^T, Vp = V@Wv^T
//   S = scale * Qh Kh^T, strict causal (j <= i-1), softmax, row0 zeroed
//   out = P@Vp ; Vhat = out@Wo^T  (fp32 output)
// Precision: hi/lo bf16 split (3-term MFMA) for QK path; plain bf16 elsewhere.
// R3: barrier-free flash loop — K/V loaded global->register directly in MFMA
//     B-fragment layout (no LDS staging, no __syncthreads in the main loop);
//     6 independent QK MFMA chains; per-wave LDS only for the P transpose.
//     Keeps R2's 640-block LPT split-key segmentation + combine pass.
//     launch_bounds(256,1): R2's (256,2) caused catastrophic scratch spill
//     (VGPR 236->128, FETCH 0.2->1.2 GB).
// ---------------------------------------------------------------------------

typedef unsigned short u16;
typedef short short8 __attribute__((ext_vector_type(8)));
typedef float floatx4 __attribute__((ext_vector_type(4)));

#define L_SEQ 4096
#define NBATCH 4
#define DMODEL 512
#define SCALE 0.22097086912079612f   // 5/sqrt(512)

__device__ __forceinline__ u16 f2bf(float f) {
  unsigned int u = __float_as_uint(f);
  u += 0x7fffu + ((u >> 16) & 1u);      // round-to-nearest-even
  return (u16)(u >> 16);
}
__device__ __forceinline__ float bf2f(u16 h) {
  return __uint_as_float(((unsigned int)h) << 16);
}

// ----------------- elementwise converts ------------------------------------
__global__ __launch_bounds__(256) void split_f32(const float* __restrict__ x,
                                                 u16* __restrict__ hi,
                                                 u16* __restrict__ lo, int n) {
  int i = blockIdx.x * 256 + threadIdx.x;
  if (i >= n) return;
  float f = x[i];
  u16 h = f2bf(f);
  hi[i] = h;
  lo[i] = f2bf(f - bf2f(h));
}

__global__ __launch_bounds__(256) void cvt_f32(const float* __restrict__ x,
                                               u16* __restrict__ o, int n) {
  int i = blockIdx.x * 256 + threadIdx.x;
  if (i >= n) return;
  o[i] = f2bf(x[i]);
}

// ----------------- generic C = A * B^T GEMM (K=512 fixed) ------------------
// A[M][512], B[N][512] row-major bf16 (optionally hi/lo split -> 3-term MFMA).
// OUT_MODE: 0 = bf16 hi+lo pair, 1 = bf16, 2 = fp32.
// grid = (N/64, M/64, Z); block = 256 (4 waves, 16 rows each).
template <int IN_SPLIT, int OUT_MODE>
__global__ __launch_bounds__(256, 2) void gemm_bt(
    const u16* __restrict__ Ahi, const u16* __restrict__ Alo,
    const u16* __restrict__ Bhi, const u16* __restrict__ Blo,
    void* __restrict__ Cout, u16* __restrict__ Clo,
    int ldc, long sAz, long sBz, long sCz) {
  __shared__ u16 sAh[64 * 72];
  __shared__ u16 sAl[IN_SPLIT ? 64 * 72 : 8];
  __shared__ u16 sBh[64 * 72];
  __shared__ u16 sBl[IN_SPLIT ? 64 * 72 : 8];

  const int tid = threadIdx.x;
  const int wave = tid >> 6, lane = tid & 63, quad = lane >> 4, l16 = lane & 15;
  const int bn = blockIdx.x * 64, bm = blockIdx.y * 64, bz = blockIdx.z;

  const u16* Ah = Ahi + (long)bz * sAz;
  const u16* Al = IN_SPLIT ? (Alo + (long)bz * sAz) : nullptr;
  const u16* Bh = Bhi + (long)bz * sBz;
  const u16* Bl = IN_SPLIT ? (Blo + (long)bz * sBz) : nullptr;

  floatx4 zero = {0.f, 0.f, 0.f, 0.f};
  floatx4 acc[4];
#pragma unroll
  for (int nb = 0; nb < 4; nb++) acc[nb] = zero;

  for (int ks = 0; ks < 8; ks++) {  // K = 512 in chunks of 64
    __syncthreads();
#pragma unroll
    for (int i = 0; i < 2; i++) {
      int c = tid + 256 * i;
      int row = c >> 3, cc = c & 7;  // 8 x 16B chunks per 64-elem row
      long ga = (long)(bm + row) * 512 + ks * 64 + cc * 8;
      long gb = (long)(bn + row) * 512 + ks * 64 + cc * 8;
      int la = row * 72 + cc * 8;
      *(int4*)&sAh[la] = *(const int4*)&Ah[ga];
      *(int4*)&sBh[la] = *(const int4*)&Bh[gb];
      if (IN_SPLIT) {
        *(int4*)&sAl[la] = *(const int4*)&Al[ga];
        *(int4*)&sBl[la] = *(const int4*)&Bl[gb];
      }
    }
    __syncthreads();
#pragma unroll
    for (int kk = 0; kk < 2; kk++) {
      int aoff = (wave * 16 + l16) * 72 + kk * 32 + quad * 8;
      short8 ah = *(const short8*)&sAh[aoff];
      short8 al;
      if (IN_SPLIT) al = *(const short8*)&sAl[aoff];
#pragma unroll
      for (int nb = 0; nb < 4; nb++) {
        int boff = (nb * 16 + l16) * 72 + kk * 32 + quad * 8;
        short8 bh = *(const short8*)&sBh[boff];
        acc[nb] = __builtin_amdgcn_mfma_f32_16x16x32_bf16(ah, bh, acc[nb], 0, 0, 0);
        if (IN_SPLIT) {
          short8 bl = *(const short8*)&sBl[boff];
          acc[nb] = __builtin_amdgcn_mfma_f32_16x16x32_bf16(ah, bl, acc[nb], 0, 0, 0);
          acc[nb] = __builtin_amdgcn_mfma_f32_16x16x32_bf16(al, bh, acc[nb], 0, 0, 0);
        }
      }
    }
  }

#pragma unroll
  for (int nb = 0; nb < 4; nb++) {
#pragma unroll
    for (int rr = 0; rr < 4; rr++) {
      int row = bm + wave * 16 + quad * 4 + rr;
      int col = bn + nb * 16 + l16;
      long idx = (long)bz * sCz + (long)row * ldc + col;
      float v = acc[nb][rr];
      if (OUT_MODE == 0) {
        u16 h = f2bf(v);
        ((u16*)Cout)[idx] = h;
        Clo[idx] = f2bf(v - bf2f(h));
      } else if (OUT_MODE == 1) {
        ((u16*)Cout)[idx] = f2bf(v);
      } else {
        ((float*)Cout)[idx] = v;
      }
    }
  }
}

// ----------------- segmented flash attention (barrier-free) -----------------
// Jobs: for qt = 63..0, for b = 0..3, for s = 0..S(qt)-1 where
// S(qt) = ceil((qt+1)/16) in {1,2,3,4}. Total = 640 blocks (LPT order).
// Each block: 64 queries (4 waves x 16), key segment of <= 32 key-tiles (32
// keys each). S==1 (qt<16): write normalized O direct. Else: write
// unnormalized bf16 O~ + fp32 (m,l) partials for the combine pass.
__device__ __forceinline__ int nseg_of(int qt) {
  return 1 + (qt >= 16) + (qt >= 32) + (qt >= 48);
}

__global__ __launch_bounds__(256, 1) void attn_kernel(
    const u16* __restrict__ Qhi_g, const u16* __restrict__ Qlo_g,
    const u16* __restrict__ Khi_g, const u16* __restrict__ Klo_g,
    const u16* __restrict__ VpT, u16* __restrict__ Ob,
    u16* __restrict__ Opart, float* __restrict__ ml) {
  __shared__ u16 sP[4 * 16 * 40]; // per-wave P [16 q][32 keys] pad->40 (5 KB)

  const int tid = threadIdx.x;
  const int wave = tid >> 6, lane = tid & 63, quad = lane >> 4, l16 = lane & 15;

  // ---- decode job: (qt descending, batch, segment) ----
  int id = blockIdx.x;
  int qt = 63;
  for (;;) {
    int c = 4 * nseg_of(qt);
    if (id < c) break;
    id -= c;
    qt--;
  }
  const int S = nseg_of(qt);
  const int b = id / S;
  const int s = id - b * S;
  const int ktn = 2 * qt + 2;           // total 32-key tiles for this q-tile
  const int base = ktn / S, rem = ktn - base * S;
  const int len = base + (s < rem);
  const int start = s * base + (s < rem ? s : rem);

  const int q0 = qt * 64 + wave * 16;   // wave's first query row (in batch)
  const long qbase = (long)b * L_SEQ + q0;

  // Q fragments (A-layout: lane&15 = row, k = quad*8 + j), resident in regs.
  short8 qhi[16], qlo[16];
#pragma unroll
  for (int kkk = 0; kkk < 16; kkk++) {
    long a = (qbase + l16) * 512 + kkk * 32 + quad * 8;
    qhi[kkk] = *(const short8*)&Qhi_g[a];
    qlo[kkk] = *(const short8*)&Qlo_g[a];
  }

  floatx4 zero = {0.f, 0.f, 0.f, 0.f};
  float m_run[4] = {-1e30f, -1e30f, -1e30f, -1e30f};
  float l_run[4] = {0.f, 0.f, 0.f, 0.f};
  floatx4 oacc[32];
#pragma unroll
  for (int nb = 0; nb < 32; nb++) oacc[nb] = zero;

  // base pointers for this block's batch
  const u16* __restrict__ Kh_b = Khi_g + (long)b * L_SEQ * 512;
  const u16* __restrict__ Kl_b = Klo_g + (long)b * L_SEQ * 512;
  const u16* __restrict__ V_b  = VpT + (long)b * (512L * L_SEQ);

  for (int v = 0; v < len; v++) {
    const int j0 = (start + v) * 32;

    // ---- S = Qh Kh^T, K loaded direct global->reg in B-frag layout ----
    // 6 independent accumulator chains (3 terms x 2 key sub-tiles).
    const u16* Kh0 = &Kh_b[(long)(j0 + l16) * 512 + quad * 8];
    const u16* Kl0 = &Kl_b[(long)(j0 + l16) * 512 + quad * 8];
    const u16* Kh1 = Kh0 + 16 * 512;
    const u16* Kl1 = Kl0 + 16 * 512;
    floatx4 s0hh = zero, s0lh = zero, s0hl = zero;
    floatx4 s1hh = zero, s1lh = zero, s1hl = zero;
#pragma unroll
    for (int c = 0; c < 16; c++) {
      short8 bh0 = *(const short8*)&Kh0[c * 32];
      short8 bl0 = *(const short8*)&Kl0[c * 32];
      short8 bh1 = *(const short8*)&Kh1[c * 32];
      short8 bl1 = *(const short8*)&Kl1[c * 32];
      s0hh = __builtin_amdgcn_mfma_f32_16x16x32_bf16(qhi[c], bh0, s0hh, 0, 0, 0);
      s1hh = __builtin_amdgcn_mfma_f32_16x16x32_bf16(qhi[c], bh1, s1hh, 0, 0, 0);
      s0lh = __builtin_amdgcn_mfma_f32_16x16x32_bf16(qlo[c], bh0, s0lh, 0, 0, 0);
      s1lh = __builtin_amdgcn_mfma_f32_16x16x32_bf16(qlo[c], bh1, s1lh, 0, 0, 0);
      s0hl = __builtin_amdgcn_mfma_f32_16x16x32_bf16(qhi[c], bl0, s0hl, 0, 0, 0);
      s1hl = __builtin_amdgcn_mfma_f32_16x16x32_bf16(qhi[c], bl1, s1hl, 0, 0, 0);
    }
    floatx4 sacc0 = s0hh + s0lh + s0hl;
    floatx4 sacc1 = s1hh + s1lh + s1hl;

    // ---- online softmax (fp32); C/D layout: col=lane&15, row=quad*4+rr ----
    float alpha[4];
    bool anyresc = false;
#pragma unroll
    for (int rr = 0; rr < 4; rr++) {
      int irow = q0 + quad * 4 + rr;
      float s0 = sacc0[rr] * SCALE;
      float s1 = sacc1[rr] * SCALE;
      if (j0 + l16 >= irow) s0 = -1e30f;       // strict causal: mask j >= i
      if (j0 + 16 + l16 >= irow) s1 = -1e30f;
      float mx = fmaxf(s0, s1);
      mx = fmaxf(mx, __shfl_xor(mx, 1));
      mx = fmaxf(mx, __shfl_xor(mx, 2));
      mx = fmaxf(mx, __shfl_xor(mx, 4));
      mx = fmaxf(mx, __shfl_xor(mx, 8));
      float mnew = fmaxf(m_run[rr], mx);
      float al_ = __expf(m_run[rr] - mnew);
      float p0 = __expf(s0 - mnew);
      float p1 = __expf(s1 - mnew);
      float ps = p0 + p1;
      ps += __shfl_xor(ps, 1);
      ps += __shfl_xor(ps, 2);
      ps += __shfl_xor(ps, 4);
      ps += __shfl_xor(ps, 8);
      l_run[rr] = l_run[rr] * al_ + ps;
      m_run[rr] = mnew;
      alpha[rr] = al_;
      anyresc |= (al_ != 1.0f);
      int pb = wave * 640 + (quad * 4 + rr) * 40;
      sP[pb + l16] = f2bf(p0);
      sP[pb + 16 + l16] = f2bf(p1);
    }
    if (__any((int)anyresc)) {
#pragma unroll
      for (int nb = 0; nb < 32; nb++) {
        oacc[nb][0] *= alpha[0];
        oacc[nb][1] *= alpha[1];
        oacc[nb][2] *= alpha[2];
        oacc[nb][3] *= alpha[3];
      }
    }

    // wave-internal LDS write->read ordering (cross-lane transpose):
    // wait lgkmcnt(0) only (vmcnt=63, expcnt=7 -> 0xC07F).
    __builtin_amdgcn_s_waitcnt(0xC07F);

    // ---- O += P V : P via per-wave LDS round-trip; V direct global->reg ----
    short8 ap = *(const short8*)&sP[wave * 640 + l16 * 40 + quad * 8];
    const u16* Vp0 = &V_b[(long)l16 * L_SEQ + j0 + quad * 8];
#pragma unroll
    for (int nb = 0; nb < 32; nb++) {
      short8 bv = *(const short8*)&Vp0[(long)nb * 16 * L_SEQ];
      oacc[nb] = __builtin_amdgcn_mfma_f32_16x16x32_bf16(ap, bv, oacc[nb], 0, 0, 0);
    }
  }

  // ---- epilogue ----
  if (S == 1) {
    // normalize, zero row 0, store bf16 O directly
#pragma unroll
    for (int rr = 0; rr < 4; rr++) {
      int irow = q0 + quad * 4 + rr;
      float inv = (irow == 0 || l_run[rr] <= 0.f) ? 0.f : 1.0f / l_run[rr];
      long obase = ((long)b * L_SEQ + irow) * 512;
#pragma unroll
      for (int nb = 0; nb < 32; nb++) {
        Ob[obase + nb * 16 + l16] = f2bf(oacc[nb][rr] * inv);
      }
    }
  } else {
    // partials: unnormalized bf16 O~ + fp32 (m,l) per row
    const int slot = ((qt - 16) * 4 + b) * 4 + s;
    const long obase = (long)slot * (64 * 512);
#pragma unroll
    for (int rr = 0; rr < 4; rr++) {
      int wrow = wave * 16 + quad * 4 + rr;
#pragma unroll
      for (int nb = 0; nb < 32; nb++) {
        Opart[obase + (long)wrow * 512 + nb * 16 + l16] = f2bf(oacc[nb][rr]);
      }
      if (l16 == 0) {
        ml[slot * 128 + wrow * 2] = m_run[rr];
        ml[slot * 128 + wrow * 2 + 1] = l_run[rr];
      }
    }
  }
}

// ----------------- combine pass (multi-segment q-tiles: qt in [16,63]) ------
__global__ __launch_bounds__(256) void attn_combine(
    const u16* __restrict__ Opart, const float* __restrict__ ml,
    u16* __restrict__ Ob) {
  const int qt = 16 + (blockIdx.x >> 2), b = blockIdx.x & 3;
  const int S = nseg_of(qt);
  const int bslot = ((qt - 16) * 4 + b) * 4;
  __shared__ float coef[4][64];
  const int tid = threadIdx.x;
  if (tid < 64) {
    int row = tid, irow = qt * 64 + row;
    float m[4], l[4], M = -1e30f;
    for (int s = 0; s < S; s++) {
      m[s] = ml[(bslot + s) * 128 + row * 2];
      l[s] = ml[(bslot + s) * 128 + row * 2 + 1];
      M = fmaxf(M, m[s]);
    }
    float w[4], ltot = 0.f;
    for (int s = 0; s < S; s++) {
      w[s] = __expf(m[s] - M);
      ltot += w[s] * l[s];
    }
    float inv = (irow == 0 || ltot <= 0.f) ? 0.f : 1.0f / ltot;
    for (int s = 0; s < 4; s++) coef[s][row] = (s < S) ? w[s] * inv : 0.f;
  }
  __syncthreads();
  for (int idx = tid; idx < 64 * 64; idx += 256) {  // 64 rows x 64 int4-chunks
    int row = idx >> 6, c8 = idx & 63;
    float acc[8] = {0, 0, 0, 0, 0, 0, 0, 0};
    for (int s = 0; s < S; s++) {
      int4 pk = *(const int4*)&Opart[(long)(bslot + s) * 32768 + row * 512 + c8 * 8];
      const u16* ph = (const u16*)&pk;
      float c = coef[s][row];
#pragma unroll
      for (int e = 0; e < 8; e++) acc[e] += c * bf2f(ph[e]);
    }
    u16 o[8];
#pragma unroll
    for (int e = 0; e < 8; e++) o[e] = f2bf(acc[e]);
    *(int4*)&Ob[((long)b * L_SEQ + qt * 64 + row) * 512 + c8 * 8] = *(int4*)o;
  }
}

// ---------------------------------------------------------------------------
extern "C" void kernel_launch(void* const* d_in, const int* in_sizes, int n_in,
                              void* d_out, int out_size, void* d_ws, size_t ws_size,
                              hipStream_t stream) {
  const float* K  = (const float*)d_in[0];
  const float* V  = (const float*)d_in[1];
  const float* Wq = (const float*)d_in[2];
  const float* Wk = (const float*)d_in[3];
  const float* Wv = (const float*)d_in[4];
  const float* Wo = (const float*)d_in[5];
  float* out = (float*)d_out;

  const int NKV = NBATCH * L_SEQ * DMODEL;  // 8,388,608
  const int NW = DMODEL * DMODEL;           // 262,144

  // workspace carve (~147 MB)
  char* w = (char*)d_ws;
  size_t off = 0;
  auto carve = [&](size_t bytes) {
    void* p = w + off;
    off += (bytes + 255) & ~(size_t)255;
    return p;
  };
  u16* Khi  = (u16*)carve((size_t)NKV * 2);
  u16* Klo  = (u16*)carve((size_t)NKV * 2);
  u16* Vb   = (u16*)carve((size_t)NKV * 2);
  u16* Qhhi = (u16*)carve((size_t)NKV * 2);
  u16* Qhlo = (u16*)carve((size_t)NKV * 2);
  u16* Khhi = (u16*)carve((size_t)NKV * 2);
  u16* Khlo = (u16*)carve((size_t)NKV * 2);
  u16* VpTw = (u16*)carve((size_t)NKV * 2);
  u16* Obw  = (u16*)carve((size_t)NKV * 2);
  u16* Wqhi = (u16*)carve((size_t)NW * 2);
  u16* Wqlo = (u16*)carve((size_t)NW * 2);
  u16* Wkhi = (u16*)carve((size_t)NW * 2);
  u16* Wklo = (u16*)carve((size_t)NW * 2);
  u16* Wvb  = (u16*)carve((size_t)NW * 2);
  u16* Wob  = (u16*)carve((size_t)NW * 2);

  // Overlays (regions dead by the time attention runs):
  //  Opart: 768 slots x 64q x 512dv bf16 = 50,331,648 B == Khi+Klo+Vb exactly.
  //  ml:    768 slots x 64 rows x {m,l} fp32 = 393,216 B <= Wqhi region.
  u16* Opart = Khi;
  float* mlw = (float*)Wqhi;

  // 1) converts
  split_f32<<<NKV / 256, 256, 0, stream>>>(K, Khi, Klo, NKV);
  split_f32<<<NW / 256, 256, 0, stream>>>(Wq, Wqhi, Wqlo, NW);
  split_f32<<<NW / 256, 256, 0, stream>>>(Wk, Wkhi, Wklo, NW);
  cvt_f32<<<NKV / 256, 256, 0, stream>>>(V, Vb, NKV);
  cvt_f32<<<NW / 256, 256, 0, stream>>>(Wv, Wvb, NW);
  cvt_f32<<<NW / 256, 256, 0, stream>>>(Wo, Wob, NW);

  // 2) Qh = K Wq^T, Kh = K Wk^T  (split in, hi/lo out)  M=16384, N=512
  gemm_bt<1, 0><<<dim3(8, 256, 1), 256, 0, stream>>>(
      Khi, Klo, Wqhi, Wqlo, (void*)Qhhi, Qhlo, 512, 0, 0, 0);
  gemm_bt<1, 0><<<dim3(8, 256, 1), 256, 0, stream>>>(
      Khi, Klo, Wkhi, Wklo, (void*)Khhi, Khlo, 512, 0, 0, 0);

  // 3) VpT_b = Wv V_b^T : M=512 (dv), N=4096 (seq), per batch (z)
  gemm_bt<0, 1><<<dim3(64, 8, NBATCH), 256, 0, stream>>>(
      Wvb, nullptr, Vb, nullptr, (void*)VpTw, nullptr,
      L_SEQ, 0, (long)L_SEQ * 512, (long)512 * L_SEQ);

  // 4) segmented flash attention -> Ob (bf16) + partials; then combine
  attn_kernel<<<dim3(640, 1, 1), 256, 0, stream>>>(
      Qhhi, Qhlo, Khhi, Khlo, VpTw, Obw, Opart, mlw);
  attn_combine<<<dim3(192, 1, 1), 256, 0, stream>>>(Opart, mlw, Obw);

  // 5) Vhat = Ob Wo^T -> fp32 d_out   M=16384, N=512
  gemm_bt<0, 2><<<dim3(8, 256, 1), 256, 0, stream>>>(
      Obw, nullptr, Wob, nullptr, (void*)out, nullptr, 512, 0, 0, 0);

  (void)in_sizes; (void)n_in; (void)out_size; (void)ws_size;
}

// Round 4
// 732.080 us; speedup vs baseline: 1.7697x; 1.7697x over previous
//
#include <hip/hip_runtime.h>

// ---------------------------------------------------------------------------
// FrozenSoftmaxAttention: B=4, L=4096, d=dv=dh=512
//   Qh = K@Wq^T, Kh = K@Wk^T, Vp = V@Wv^T
//   S = scale * Qh Kh^T, strict causal (j <= i-1), softmax, row0 zeroed
//   out = P@Vp ; Vhat = out@Wo^T  (fp32 output)
// R4: f16 score path. Projections computed accurately (bf16 hi/lo split
//     3-term MFMA, fp32 accum) then stored as f16 single (rel err 2^-11,
//     score sigma ~0.004 -> absmax ~0.03). Attention QK = single f16 MFMA
//     chain (3x fewer MFMAs, half LDS traffic vs R1), K staged in ONE shot
//     (2 barriers/visit vs 9), LDS 79 KB -> 2 blocks/CU co-residency.
//     Vp/P/O/Wo path f16 everywhere (better than R1's bf16).
//     R2 lesson: (256,2) only safe because footprint ~250 <= 256 regs.
//     R3 lesson: keep LDS staging (dedup across 4 waves) — direct global
//     B-frags quadruple L2 traffic and expose latency.
// ---------------------------------------------------------------------------

typedef unsigned short u16;
typedef _Float16 f16;
typedef short short8 __attribute__((ext_vector_type(8)));
typedef _Float16 half8 __attribute__((ext_vector_type(8)));
typedef float floatx4 __attribute__((ext_vector_type(4)));

#define L_SEQ 4096
#define NBATCH 4
#define DMODEL 512
#define SCALE 0.22097086912079612f   // 5/sqrt(512)

__device__ __forceinline__ u16 f2bf(float f) {
  unsigned int u = __float_as_uint(f);
  u += 0x7fffu + ((u >> 16) & 1u);      // round-to-nearest-even
  return (u16)(u >> 16);
}
__device__ __forceinline__ float bf2f(u16 h) {
  return __uint_as_float(((unsigned int)h) << 16);
}

// ----------------- elementwise converts ------------------------------------
__global__ __launch_bounds__(256) void split_f32(const float* __restrict__ x,
                                                 u16* __restrict__ hi,
                                                 u16* __restrict__ lo, int n) {
  int i = blockIdx.x * 256 + threadIdx.x;
  if (i >= n) return;
  float f = x[i];
  u16 h = f2bf(f);
  hi[i] = h;
  lo[i] = f2bf(f - bf2f(h));
}

__global__ __launch_bounds__(256) void cvt_f16(const float* __restrict__ x,
                                               f16* __restrict__ o, int n) {
  int i = blockIdx.x * 256 + threadIdx.x;
  if (i >= n) return;
  o[i] = (f16)x[i];
}

// ----------------- generic C = A * B^T GEMM (K=512 fixed) ------------------
// IN_SPLIT=1: A,B are bf16 hi/lo pairs, 3-term bf16 MFMA (accurate path).
// IN_SPLIT=0: A,B are f16, single f16 MFMA.
// OUT_MODE: 1 = f16, 2 = fp32.
// grid = (N/64, M/64, Z); block = 256 (4 waves, 16 rows each).
template <int IN_SPLIT, int OUT_MODE>
__global__ __launch_bounds__(256, 2) void gemm_bt(
    const u16* __restrict__ Ahi, const u16* __restrict__ Alo,
    const u16* __restrict__ Bhi, const u16* __restrict__ Blo,
    void* __restrict__ Cout,
    int ldc, long sAz, long sBz, long sCz) {
  __shared__ u16 sAh[64 * 72];
  __shared__ u16 sAl[IN_SPLIT ? 64 * 72 : 8];
  __shared__ u16 sBh[64 * 72];
  __shared__ u16 sBl[IN_SPLIT ? 64 * 72 : 8];

  const int tid = threadIdx.x;
  const int wave = tid >> 6, lane = tid & 63, quad = lane >> 4, l16 = lane & 15;
  const int bn = blockIdx.x * 64, bm = blockIdx.y * 64, bz = blockIdx.z;

  const u16* Ah = Ahi + (long)bz * sAz;
  const u16* Al = IN_SPLIT ? (Alo + (long)bz * sAz) : nullptr;
  const u16* Bh = Bhi + (long)bz * sBz;
  const u16* Bl = IN_SPLIT ? (Blo + (long)bz * sBz) : nullptr;

  floatx4 zero = {0.f, 0.f, 0.f, 0.f};
  floatx4 acc[4];
#pragma unroll
  for (int nb = 0; nb < 4; nb++) acc[nb] = zero;

  for (int ks = 0; ks < 8; ks++) {  // K = 512 in chunks of 64
    __syncthreads();
#pragma unroll
    for (int i = 0; i < 2; i++) {
      int c = tid + 256 * i;
      int row = c >> 3, cc = c & 7;  // 8 x 16B chunks per 64-elem row
      long ga = (long)(bm + row) * 512 + ks * 64 + cc * 8;
      long gb = (long)(bn + row) * 512 + ks * 64 + cc * 8;
      int la = row * 72 + cc * 8;
      *(int4*)&sAh[la] = *(const int4*)&Ah[ga];
      *(int4*)&sBh[la] = *(const int4*)&Bh[gb];
      if (IN_SPLIT) {
        *(int4*)&sAl[la] = *(const int4*)&Al[ga];
        *(int4*)&sBl[la] = *(const int4*)&Bl[gb];
      }
    }
    __syncthreads();
#pragma unroll
    for (int kk = 0; kk < 2; kk++) {
      int aoff = (wave * 16 + l16) * 72 + kk * 32 + quad * 8;
#pragma unroll
      for (int nb = 0; nb < 4; nb++) {
        int boff = (nb * 16 + l16) * 72 + kk * 32 + quad * 8;
        if (IN_SPLIT) {
          short8 ah = *(const short8*)&sAh[aoff];
          short8 al = *(const short8*)&sAl[aoff];
          short8 bh = *(const short8*)&sBh[boff];
          short8 bl = *(const short8*)&sBl[boff];
          acc[nb] = __builtin_amdgcn_mfma_f32_16x16x32_bf16(ah, bh, acc[nb], 0, 0, 0);
          acc[nb] = __builtin_amdgcn_mfma_f32_16x16x32_bf16(ah, bl, acc[nb], 0, 0, 0);
          acc[nb] = __builtin_amdgcn_mfma_f32_16x16x32_bf16(al, bh, acc[nb], 0, 0, 0);
        } else {
          half8 ah = *(const half8*)&sAh[aoff];
          half8 bh = *(const half8*)&sBh[boff];
          acc[nb] = __builtin_amdgcn_mfma_f32_16x16x32_f16(ah, bh, acc[nb], 0, 0, 0);
        }
      }
    }
  }

#pragma unroll
  for (int nb = 0; nb < 4; nb++) {
#pragma unroll
    for (int rr = 0; rr < 4; rr++) {
      int row = bm + wave * 16 + quad * 4 + rr;
      int col = bn + nb * 16 + l16;
      long idx = (long)bz * sCz + (long)row * ldc + col;
      float v = acc[nb][rr];
      if (OUT_MODE == 1) {
        ((f16*)Cout)[idx] = (f16)v;
      } else {
        ((float*)Cout)[idx] = v;
      }
    }
  }
}

// ----------------- segmented flash attention (f16) --------------------------
// Jobs: for qt = 63..0, for b = 0..3, for s = 0..S(qt)-1 where
// S(qt) = ceil((qt+1)/16) in {1,2,3,4}. Total = 640 blocks (LPT order).
// Each block: 64 queries (4 waves x 16), key segment of <= 32 key-tiles (32
// keys each). S==1 (qt<16): write normalized O direct. Else: write
// unnormalized f16 O~ + fp32 (m,l) partials for the combine pass.
__device__ __forceinline__ int nseg_of(int qt) {
  return 1 + (qt >= 16) + (qt >= 32) + (qt >= 48);
}

#define SK_LD 520   // K tile row stride (elems): 16B aligned, reads 2-way free
#define SV_LD 40    // V tile row stride (elems), proven R1 layout

__global__ __launch_bounds__(256, 2) void attn_kernel(
    const f16* __restrict__ Qh_g, const f16* __restrict__ Kh_g,
    const f16* __restrict__ VpT, f16* __restrict__ Ob,
    f16* __restrict__ Opart, float* __restrict__ ml) {
  __shared__ f16 sK[32 * SK_LD];     // 33280 B: [32 keys][512 k]
  __shared__ f16 sV[512 * SV_LD];    // 40960 B: [512 dv][32 keys]
  __shared__ f16 sP[4 * 16 * SV_LD]; // 5120 B: per-wave P [16 q][32 keys]

  const int tid = threadIdx.x;
  const int wave = tid >> 6, lane = tid & 63, quad = lane >> 4, l16 = lane & 15;

  // ---- decode job: (qt descending, batch, segment) ----
  int id = blockIdx.x;
  int qt = 63;
  for (;;) {
    int c = 4 * nseg_of(qt);
    if (id < c) break;
    id -= c;
    qt--;
  }
  const int S = nseg_of(qt);
  const int b = id / S;
  const int s = id - b * S;
  const int ktn = 2 * qt + 2;           // total 32-key tiles for this q-tile
  const int base = ktn / S, rem = ktn - base * S;
  const int len = base + (s < rem);
  const int start = s * base + (s < rem ? s : rem);

  const int q0 = qt * 64 + wave * 16;   // wave's first query row (in batch)
  const long qbase = (long)b * L_SEQ + q0;

  // Q fragments (A-layout: lane&15 = row, k = quad*8 + j), resident in regs.
  half8 qf[16];
#pragma unroll
  for (int c = 0; c < 16; c++) {
    long a = (qbase + l16) * 512 + c * 32 + quad * 8;
    qf[c] = *(const half8*)&Qh_g[a];
  }

  floatx4 zero = {0.f, 0.f, 0.f, 0.f};
  float m_run[4] = {-1e30f, -1e30f, -1e30f, -1e30f};
  float l_run[4] = {0.f, 0.f, 0.f, 0.f};
  floatx4 oacc[32];
#pragma unroll
  for (int nb = 0; nb < 32; nb++) oacc[nb] = zero;

  const f16* __restrict__ Kh_b = Kh_g + (long)b * L_SEQ * 512;
  const f16* __restrict__ V_b  = VpT + (long)b * (512L * L_SEQ);

  for (int v = 0; v < len; v++) {
    const int j0 = (start + v) * 32;

    __syncthreads();  // protect previous iteration's sK/sV reads
    // ---- stage K tile [32 keys][512] in one shot: thread t -> row t>>3,
    //      8 lanes/row each 16B, 8 chunk-iters (128B contiguous per 8 lanes)
    {
      const int r = tid >> 3, c0 = tid & 7;
      const f16* gsrc = Kh_b + (long)(j0 + r) * 512 + c0 * 8;
      f16* ldst = sK + r * SK_LD + c0 * 8;
#pragma unroll
      for (int i = 0; i < 8; i++)
        *(int4*)(ldst + i * 64) = *(const int4*)(gsrc + i * 64);
    }
    // ---- stage V tile [512 dv][32 keys] ----
#pragma unroll
    for (int i = 0; i < 8; i++) {
      int c = tid + 256 * i;
      int row = c >> 2, cc = c & 3;  // 4 x 16B chunks per 32-elem row
      long g = (long)row * L_SEQ + j0 + cc * 8;
      *(int4*)&sV[row * SV_LD + cc * 8] = *(const int4*)&V_b[g];
    }
    __syncthreads();

    // ---- S = Qh Kh^T : single f16 MFMA chain, 2 key sub-tiles ----
    floatx4 sacc0 = zero, sacc1 = zero;
#pragma unroll
    for (int c = 0; c < 16; c++) {
      int off = c * 32 + quad * 8;
      half8 b0 = *(const half8*)&sK[l16 * SK_LD + off];
      half8 b1 = *(const half8*)&sK[(16 + l16) * SK_LD + off];
      sacc0 = __builtin_amdgcn_mfma_f32_16x16x32_f16(qf[c], b0, sacc0, 0, 0, 0);
      sacc1 = __builtin_amdgcn_mfma_f32_16x16x32_f16(qf[c], b1, sacc1, 0, 0, 0);
    }

    // ---- online softmax (fp32); C/D layout: col=lane&15, row=quad*4+rr ----
    float alpha[4];
    bool anyresc = false;
#pragma unroll
    for (int rr = 0; rr < 4; rr++) {
      int irow = q0 + quad * 4 + rr;
      float s0 = sacc0[rr] * SCALE;
      float s1 = sacc1[rr] * SCALE;
      if (j0 + l16 >= irow) s0 = -1e30f;       // strict causal: mask j >= i
      if (j0 + 16 + l16 >= irow) s1 = -1e30f;
      float mx = fmaxf(s0, s1);
      mx = fmaxf(mx, __shfl_xor(mx, 1));
      mx = fmaxf(mx, __shfl_xor(mx, 2));
      mx = fmaxf(mx, __shfl_xor(mx, 4));
      mx = fmaxf(mx, __shfl_xor(mx, 8));
      float mnew = fmaxf(m_run[rr], mx);
      float al_ = __expf(m_run[rr] - mnew);
      float p0 = __expf(s0 - mnew);
      float p1 = __expf(s1 - mnew);
      float ps = p0 + p1;
      ps += __shfl_xor(ps, 1);
      ps += __shfl_xor(ps, 2);
      ps += __shfl_xor(ps, 4);
      ps += __shfl_xor(ps, 8);
      l_run[rr] = l_run[rr] * al_ + ps;
      m_run[rr] = mnew;
      alpha[rr] = al_;
      anyresc |= (al_ != 1.0f);
      int pb = wave * 640 + (quad * 4 + rr) * SV_LD;
      sP[pb + l16] = (f16)p0;
      sP[pb + 16 + l16] = (f16)p1;
    }
    if (__any((int)anyresc)) {
#pragma unroll
      for (int nb = 0; nb < 32; nb++) {
        oacc[nb][0] *= alpha[0];
        oacc[nb][1] *= alpha[1];
        oacc[nb][2] *= alpha[2];
        oacc[nb][3] *= alpha[3];
      }
    }

    // wave-internal LDS write->read ordering for the P transpose:
    // wait lgkmcnt(0) only (vmcnt=63, expcnt=7 -> 0xC07F).
    __builtin_amdgcn_s_waitcnt(0xC07F);

    // ---- O += P V ----
    half8 ap = *(const half8*)&sP[wave * 640 + l16 * SV_LD + quad * 8];
#pragma unroll
    for (int nb = 0; nb < 32; nb++) {
      half8 bv = *(const half8*)&sV[(nb * 16 + l16) * SV_LD + quad * 8];
      oacc[nb] = __builtin_amdgcn_mfma_f32_16x16x32_f16(ap, bv, oacc[nb], 0, 0, 0);
    }
  }

  // ---- epilogue ----
  if (S == 1) {
#pragma unroll
    for (int rr = 0; rr < 4; rr++) {
      int irow = q0 + quad * 4 + rr;
      float inv = (irow == 0 || l_run[rr] <= 0.f) ? 0.f : 1.0f / l_run[rr];
      long obase = ((long)b * L_SEQ + irow) * 512;
#pragma unroll
      for (int nb = 0; nb < 32; nb++) {
        Ob[obase + nb * 16 + l16] = (f16)(oacc[nb][rr] * inv);
      }
    }
  } else {
    const int slot = ((qt - 16) * 4 + b) * 4 + s;
    const long obase = (long)slot * (64 * 512);
#pragma unroll
    for (int rr = 0; rr < 4; rr++) {
      int wrow = wave * 16 + quad * 4 + rr;
#pragma unroll
      for (int nb = 0; nb < 32; nb++) {
        Opart[obase + (long)wrow * 512 + nb * 16 + l16] = (f16)oacc[nb][rr];
      }
      if (l16 == 0) {
        ml[slot * 128 + wrow * 2] = m_run[rr];
        ml[slot * 128 + wrow * 2 + 1] = l_run[rr];
      }
    }
  }
}

// ----------------- combine pass (multi-segment q-tiles: qt in [16,63]) ------
__global__ __launch_bounds__(256) void attn_combine(
    const f16* __restrict__ Opart, const float* __restrict__ ml,
    f16* __restrict__ Ob) {
  const int qt = 16 + (blockIdx.x >> 2), b = blockIdx.x & 3;
  const int S = nseg_of(qt);
  const int bslot = ((qt - 16) * 4 + b) * 4;
  __shared__ float coef[4][64];
  const int tid = threadIdx.x;
  if (tid < 64) {
    int row = tid, irow = qt * 64 + row;
    float m[4], l[4], M = -1e30f;
    for (int s = 0; s < S; s++) {
      m[s] = ml[(bslot + s) * 128 + row * 2];
      l[s] = ml[(bslot + s) * 128 + row * 2 + 1];
      M = fmaxf(M, m[s]);
    }
    float w[4], ltot = 0.f;
    for (int s = 0; s < S; s++) {
      w[s] = __expf(m[s] - M);
      ltot += w[s] * l[s];
    }
    float inv = (irow == 0 || ltot <= 0.f) ? 0.f : 1.0f / ltot;
    for (int s = 0; s < 4; s++) coef[s][row] = (s < S) ? w[s] * inv : 0.f;
  }
  __syncthreads();
  for (int idx = tid; idx < 64 * 64; idx += 256) {  // 64 rows x 64 int4-chunks
    int row = idx >> 6, c8 = idx & 63;
    float acc[8] = {0, 0, 0, 0, 0, 0, 0, 0};
    for (int s = 0; s < S; s++) {
      int4 pk = *(const int4*)&Opart[(long)(bslot + s) * 32768 + row * 512 + c8 * 8];
      const f16* ph = (const f16*)&pk;
      float c = coef[s][row];
#pragma unroll
      for (int e = 0; e < 8; e++) acc[e] += c * (float)ph[e];
    }
    f16 o[8];
#pragma unroll
    for (int e = 0; e < 8; e++) o[e] = (f16)acc[e];
    *(int4*)&Ob[((long)b * L_SEQ + qt * 64 + row) * 512 + c8 * 8] = *(int4*)o;
  }
}

// ---------------------------------------------------------------------------
extern "C" void kernel_launch(void* const* d_in, const int* in_sizes, int n_in,
                              void* d_out, int out_size, void* d_ws, size_t ws_size,
                              hipStream_t stream) {
  const float* K  = (const float*)d_in[0];
  const float* V  = (const float*)d_in[1];
  const float* Wq = (const float*)d_in[2];
  const float* Wk = (const float*)d_in[3];
  const float* Wv = (const float*)d_in[4];
  const float* Wo = (const float*)d_in[5];
  float* out = (float*)d_out;

  const int NKV = NBATCH * L_SEQ * DMODEL;  // 8,388,608
  const int NW = DMODEL * DMODEL;           // 262,144

  char* w = (char*)d_ws;
  size_t off = 0;
  auto carve = [&](size_t bytes) {
    void* p = w + off;
    off += (bytes + 255) & ~(size_t)255;
    return p;
  };
  u16* Khi  = (u16*)carve((size_t)NKV * 2);   // bf16 hi of K (proj input)
  u16* Klo  = (u16*)carve((size_t)NKV * 2);   // bf16 lo of K
  f16* Vb   = (f16*)carve((size_t)NKV * 2);   // f16 V
  f16* Qh   = (f16*)carve((size_t)NKV * 2);   // f16 Qh
  f16* Kh   = (f16*)carve((size_t)NKV * 2);   // f16 Kh
  f16* VpTw = (f16*)carve((size_t)NKV * 2);   // f16 Vp^T [b][dv][seq]
  f16* Obw  = (f16*)carve((size_t)NKV * 2);   // f16 attention output
  u16* Wqhi = (u16*)carve((size_t)NW * 2);
  u16* Wqlo = (u16*)carve((size_t)NW * 2);
  u16* Wkhi = (u16*)carve((size_t)NW * 2);
  u16* Wklo = (u16*)carve((size_t)NW * 2);
  f16* Wvb  = (f16*)carve((size_t)NW * 2);
  f16* Wob  = (f16*)carve((size_t)NW * 2);

  // Overlays (dead by attention time):
  //  Opart: 768 slots x 64q x 512dv f16 = 50,331,648 B == Khi+Klo+Vb region.
  //  ml:    768 x 64 x 2 fp32 = 393,216 B <= Wqhi region (dead after projs).
  f16* Opart = (f16*)Khi;
  float* mlw = (float*)Wqhi;

  // 1) converts
  split_f32<<<NKV / 256, 256, 0, stream>>>(K, Khi, Klo, NKV);
  split_f32<<<NW / 256, 256, 0, stream>>>(Wq, Wqhi, Wqlo, NW);
  split_f32<<<NW / 256, 256, 0, stream>>>(Wk, Wkhi, Wklo, NW);
  cvt_f16<<<NKV / 256, 256, 0, stream>>>(V, Vb, NKV);
  cvt_f16<<<NW / 256, 256, 0, stream>>>(Wv, Wvb, NW);
  cvt_f16<<<NW / 256, 256, 0, stream>>>(Wo, Wob, NW);

  // 2) Qh = K Wq^T, Kh = K Wk^T  (bf16-split accurate, f16 out)  M=16384,N=512
  gemm_bt<1, 1><<<dim3(8, 256, 1), 256, 0, stream>>>(
      Khi, Klo, Wqhi, Wqlo, (void*)Qh, 512, 0, 0, 0);
  gemm_bt<1, 1><<<dim3(8, 256, 1), 256, 0, stream>>>(
      Khi, Klo, Wkhi, Wklo, (void*)Kh, 512, 0, 0, 0);

  // 3) VpT_b = Wv V_b^T : M=512 (dv), N=4096 (seq), per batch (z), f16
  gemm_bt<0, 1><<<dim3(64, 8, NBATCH), 256, 0, stream>>>(
      (const u16*)Wvb, nullptr, (const u16*)Vb, nullptr, (void*)VpTw,
      L_SEQ, 0, (long)L_SEQ * 512, (long)512 * L_SEQ);

  // 4) segmented flash attention -> Ob (f16) + partials; then combine
  attn_kernel<<<dim3(640, 1, 1), 256, 0, stream>>>(
      Qh, Kh, VpTw, Obw, Opart, mlw);
  attn_combine<<<dim3(192, 1, 1), 256, 0, stream>>>(Opart, mlw, Obw);

  // 5) Vhat = Ob Wo^T -> fp32 d_out   M=16384, N=512
  gemm_bt<0, 2><<<dim3(8, 256, 1), 256, 0, stream>>>(
      (const u16*)Obw, nullptr, (const u16*)Wob, nullptr, (void*)out,
      512, 0, 0, 0);

  (void)in_sizes; (void)n_in; (void)out_size; (void)ws_size;
}